// Round 1
// 3975.634 us; speedup vs baseline: 1.4380x; 1.4380x over previous
//
#include <hip/hip_runtime.h>
#include <hip/hip_bf16.h>
#include <math.h>

#define B_  16
#define T_  250
#define E_  512
#define H_  1024
#define V_  32000
#define M_  (B_*T_)     // 4000 token rows
#define H3_ (3*H_)      // 3072
#define NWG 64

typedef __bf16 bf16;
typedef bf16  bf16x4 __attribute__((ext_vector_type(4)));
typedef bf16  bf16x8 __attribute__((ext_vector_type(8)));
typedef float f32x4  __attribute__((ext_vector_type(4)));

// async global->LDS, 16B per lane, LDS dest = wave-uniform base + lane*16
#define GLOAD_LDS16(g, l) __builtin_amdgcn_global_load_lds( \
    (const __attribute__((address_space(1))) void*)(g), \
    (__attribute__((address_space(3))) void*)(l), 16, 0, 0)

// ---------------- contiguous f32 -> bf16 ----------------
__global__ void k_cvt(const float* __restrict__ s, bf16* __restrict__ d, int n4) {
    int i = blockIdx.x * blockDim.x + threadIdx.x;
    if (i >= n4) return;
    float4 v = ((const float4*)s)[i];
    bf16x4 o = {(bf16)v.x, (bf16)v.y, (bf16)v.z, (bf16)v.w};
    ((bf16x4*)d)[i] = o;
}

// ---------------- transpose-convert: f32 in[K][N] -> bf16 out[N][K], 64x64 tiles ----------------
__global__ __launch_bounds__(256)
void k_cvtT(const float* __restrict__ in, bf16* __restrict__ out, int K, int N) {
    __shared__ float t[64][65];           // +1 pad: conflict-free column read
    const int n0 = blockIdx.x * 64, k0 = blockIdx.y * 64;
    const int tx = threadIdx.x & 63, ty = threadIdx.x >> 6;   // 64 x 4
#pragma unroll
    for (int i = 0; i < 64; i += 4)
        t[ty + i][tx] = in[(size_t)(k0 + ty + i) * N + n0 + tx];   // t[k][n], coalesced
    __syncthreads();
#pragma unroll
    for (int i = 0; i < 64; i += 4)
        out[(size_t)(n0 + ty + i) * K + k0 + tx] = (bf16)t[tx][ty + i];  // out[n][k], coalesced
}

// ---------------- embedding gather -> bf16 A matrix [4000][512] ----------------
__global__ void k_gather(const int* __restrict__ tok, const float* __restrict__ emb,
                         bf16* __restrict__ A) {
    int r = blockIdx.x;            // 0..3999
    int t = tok[r];
    float4 v = ((const float4*)(emb + (size_t)t * E_))[threadIdx.x];   // 128 thr * 4
    bf16x4 o = {(bf16)v.x, (bf16)v.y, (bf16)v.z, (bf16)v.w};
    ((bf16x4*)(A + (size_t)r * E_))[threadIdx.x] = o;
}

// ---------------- GEMM: C[M x N] = A[M x K] * Bt[N x K]^T (+bias) ----------------
// m97-ladder structure: 128x128 tile, BK=32, global_load_lds w=16, 4 waves 2x2, 4x4 frags/wave.
// MODE 0: bf16 out (x_proj)   MODE 1: f32 out (logits)
template <int MODE>
__global__ __launch_bounds__(256, 2)
void k_gemm(const bf16* __restrict__ A, const bf16* __restrict__ Bt,
            const float* __restrict__ bias, void* __restrict__ Cout,
            int Mtiles, int K, int ldc) {
    const int mt = blockIdx.x % Mtiles;
    const int nt = blockIdx.x / Mtiles;
    const int m0 = mt * 128, n0 = nt * 128;
    __shared__ bf16 sA[128][32];   // linear (global_load_lds requirement)
    __shared__ bf16 sB[128][32];   // rows of Bt (= columns of B)
    const int tid = threadIdx.x;
    const int wave = tid >> 6, lane = tid & 63;
    const int quad = lane >> 4, l16 = lane & 15;
    const int wm = wave >> 1, wn = wave & 1;   // 2x2 wave grid, 64x64 quadrant each

    // staging: each wave stages 32 rows of A and 32 rows of Bt per K-step (2 instrs each)
    const int srow = wave * 32 + (lane >> 2);   // lane -> row within tile
    const int sbyte = (lane & 3) * 16;          // lane -> 16B chunk within 64B row
    int ar0 = m0 + srow;      if (ar0 >= M_) ar0 = M_ - 1;   // clamp: OOB rows duplicate last row
    int ar1 = m0 + srow + 16; if (ar1 >= M_) ar1 = M_ - 1;   // (masked at epilogue store)
    const int br0 = n0 + srow, br1 = n0 + srow + 16;         // N dims divide 128 exactly

    f32x4 acc[4][4] = {};

    for (int kk = 0; kk < K; kk += 32) {
        GLOAD_LDS16((const char*)(A  + (size_t)ar0 * K + kk) + sbyte, &sA[wave * 32][0]);
        GLOAD_LDS16((const char*)(A  + (size_t)ar1 * K + kk) + sbyte, &sA[wave * 32 + 16][0]);
        GLOAD_LDS16((const char*)(Bt + (size_t)br0 * K + kk) + sbyte, &sB[wave * 32][0]);
        GLOAD_LDS16((const char*)(Bt + (size_t)br1 * K + kk) + sbyte, &sB[wave * 32 + 16][0]);
        __syncthreads();   // drains vmcnt (global_load_lds) before LDS reads

        bf16x8 af[4], bfr[4];
#pragma unroll
        for (int i = 0; i < 4; i++) {
            af[i]  = *(const bf16x8*)(&sA[wm * 64 + i * 16 + l16][quad * 8]);
            bfr[i] = *(const bf16x8*)(&sB[wn * 64 + i * 16 + l16][quad * 8]);
        }
#pragma unroll
        for (int mi = 0; mi < 4; mi++)
#pragma unroll
            for (int ni = 0; ni < 4; ni++)
                acc[mi][ni] = __builtin_amdgcn_mfma_f32_16x16x32_bf16(af[mi], bfr[ni], acc[mi][ni], 0, 0, 0);
        __syncthreads();   // WAR: frags read before next stage overwrites
    }

    // epilogue: D row = quad*4+r, col = l16 (m89-verified layout)
#pragma unroll
    for (int ni = 0; ni < 4; ni++) {
        int n = n0 + wn * 64 + ni * 16 + l16;
        float bv = bias[n];
#pragma unroll
        for (int mi = 0; mi < 4; mi++) {
            int mb = m0 + wm * 64 + mi * 16 + quad * 4;
#pragma unroll
            for (int r = 0; r < 4; r++) {
                int m = mb + r;
                if (m < M_) {
                    float val = acc[mi][ni][r] + bv;
                    if (MODE == 0) ((bf16*)Cout)[(size_t)m * ldc + n] = (bf16)val;
                    else           ((float*)Cout)[(size_t)m * ldc + n] = val;
                }
            }
        }
    }
}

// ---------------- GRU recurrence: 64 persistent WGs, grid barrier per step ----------------
// h_{t-1} staged to LDS once per WG (was: 3 waves x 32 serialized global loads on the MFMA
// critical path). uf fully unrolled -> static indexing -> stays in registers (rule #20).
__global__ __launch_bounds__(256, 1)
void k_gru(const bf16* __restrict__ xproj, const float* __restrict__ U,
           const float* __restrict__ b, const float* __restrict__ h0,
           bf16* __restrict__ hA, bf16* __restrict__ hB,
           bf16* __restrict__ hs, unsigned int* __restrict__ ctr) {
    const int tid  = threadIdx.x;
    const int wave = tid >> 6, lane = tid & 63;
    const int quad = lane >> 4, l16 = lane & 15;
    const int j0 = blockIdx.x * 16;            // this WG owns hidden units j0..j0+15
    __shared__ bf16  hT[16][1032];             // row stride 2064B: b128 reads conflict-free
    __shared__ float sRec[3][16][16];          // [gate][batch][jlocal]

    // Preload U columns for this wave's gate as MFMA B-fragments (128 VGPRs, static-indexed).
    bf16x8 uf[32];
    if (wave < 3) {
        const float* Ub = U + (size_t)(wave * H_ + j0 + l16);
#pragma unroll
        for (int s = 0; s < 32; s++) {
            bf16x8 tv;
#pragma unroll
            for (int jj = 0; jj < 8; jj++)
                tv[jj] = (bf16)Ub[(size_t)(s * 32 + quad * 8 + jj) * H3_];
            uf[s] = tv;
        }
    }

    // Combine-phase identity: one (batch, hidden) pair per thread, state in f32 reg.
    const int cb = tid >> 4;          // batch 0..15
    const int cj = tid & 15;          // hidden offset
    const int j  = j0 + cj;
    const float b1z = b[H3_ + j];
    const float b1r = b[H3_ + H_ + j];
    const float b1h = b[H3_ + 2 * H_ + j];
    float hreg = h0[cb * H_ + j];

    // prefetch x_proj for t=0
    size_t xrow = (size_t)(cb * T_) * H3_;
    float xz = (float)xproj[xrow + j];
    float xr = (float)xproj[xrow + H_ + j];
    float xh = (float)xproj[xrow + 2 * H_ + j];

    for (int t = 0; t < T_; t++) {
        const bf16* hsrc = (t & 1) ? hB : hA;
        bf16*       hdst = (t & 1) ? hA : hB;

        // cooperative stage of full h_{t-1} (16x1024 bf16 = 32KB), all 4 waves,
        // 8 independent b128 loads/thread -> one latency exposure, 1x (not 3x) traffic
#pragma unroll
        for (int it = 0; it < 8; it++) {
            int c = it * 256 + tid;                    // 16B chunk id, 0..2047
            bf16x8 v = *(const bf16x8*)(hsrc + c * 8); // coalesced
            *(bf16x8*)(&hT[c >> 7][(c & 127) * 8]) = v;
        }
        __syncthreads();

        if (wave < 3) {           // rec = h_{t-1} @ U_slice  (one 16x16 tile per gate)
            f32x4 acc0 = {}, acc1 = {};
#pragma unroll
            for (int s = 0; s < 32; s += 2) {
                bf16x8 a0 = *(const bf16x8*)(&hT[l16][s * 32 + quad * 8]);
                bf16x8 a1 = *(const bf16x8*)(&hT[l16][s * 32 + 32 + quad * 8]);
                acc0 = __builtin_amdgcn_mfma_f32_16x16x32_bf16(a0, uf[s],     acc0, 0, 0, 0);
                acc1 = __builtin_amdgcn_mfma_f32_16x16x32_bf16(a1, uf[s + 1], acc1, 0, 0, 0);
            }
            f32x4 acc = acc0 + acc1;
#pragma unroll
            for (int r = 0; r < 4; r++) sRec[wave][quad * 4 + r][l16] = acc[r];
        }
        __syncthreads();

        // combine: Keras GRUCell reset_after=True
        float rz = sRec[0][cb][cj] + b1z;
        float rr = sRec[1][cb][cj] + b1r;
        float rh = sRec[2][cb][cj] + b1h;
        float az = xz + rz;  az = fminf(fmaxf(az, -30.f), 30.f);
        float ar = xr + rr;  ar = fminf(fmaxf(ar, -30.f), 30.f);
        float z = 1.f / (1.f + __expf(-az));
        float r = 1.f / (1.f + __expf(-ar));
        float ah = xh + r * rh;  ah = fminf(fmaxf(ah, -15.f), 15.f);
        float ex = __expf(2.f * ah);
        float hh = (ex - 1.f) / (ex + 1.f);
        hreg = z * hreg + (1.f - z) * hh;
        bf16 hb = (bf16)hreg;
        hdst[cb * H_ + j] = hb;
        hs[(size_t)(cb * T_ + t) * H_ + j] = hb;

        // prefetch next step's x (latency hides behind the barrier)
        if (t + 1 < T_) {
            size_t xr2 = (size_t)(cb * T_ + t + 1) * H3_;
            xz = (float)xproj[xr2 + j];
            xr = (float)xproj[xr2 + H_ + j];
            xh = (float)xproj[xr2 + 2 * H_ + j];
        }

        // grid barrier: release h writes, arrive, spin, acquire (proven pattern, unchanged)
        __threadfence();
        __syncthreads();
        if (tid == 0) {
            __hip_atomic_fetch_add(ctr, 1u, __ATOMIC_RELEASE, __HIP_MEMORY_SCOPE_AGENT);
            unsigned target = (unsigned)NWG * (t + 1);
            int guard = 0;
            while (__hip_atomic_load(ctr, __ATOMIC_RELAXED, __HIP_MEMORY_SCOPE_AGENT) < target) {
                if (++guard > (1 << 28)) break;   // fail loud (wrong result), not hung
                __builtin_amdgcn_s_sleep(1);
            }
        }
        __syncthreads();
        __threadfence();
    }
}

// ---------------- launch ----------------
extern "C" void kernel_launch(void* const* d_in, const int* in_sizes, int n_in,
                              void* d_out, int out_size, void* d_ws, size_t ws_size,
                              hipStream_t stream) {
    const int*   tok = (const int*)d_in[0];
    const float* h0  = (const float*)d_in[1];
    const float* emb = (const float*)d_in[2];
    const float* W   = (const float*)d_in[3];
    const float* U   = (const float*)d_in[4];
    const float* bb  = (const float*)d_in[5];
    const float* Wo  = (const float*)d_in[6];
    const float* bo  = (const float*)d_in[7];
    float* out = (float*)d_out;

    char* ws = (char*)d_ws;
    bf16* Wo_bT = (bf16*)(ws);                        // [V][H] bf16, 65,536,000 B
    bf16* xproj = (bf16*)(ws + 65536000);             // 24,576,000 B
    bf16* hs    = (bf16*)(ws + 90112000);             //  8,192,000 B
    bf16* Aemb  = (bf16*)(ws + 98304000);             //  4,096,000 B
    bf16* W_bT  = (bf16*)(ws + 102400000);            // [3H][E] bf16, 3,145,728 B
    bf16* hbufA = (bf16*)(ws + 105545728);            //     32,768 B
    bf16* hbufB = (bf16*)(ws + 105578496);            //     32,768 B
    unsigned* ctr = (unsigned*)(ws + 105611264);      //        256 B

    hipMemsetAsync(ctr, 0, 256, stream);

    // transpose-converts (GEMMs consume B^T rows), h0 convert, gather
    k_cvtT<<<dim3(H3_ / 64, E_ / 64), 256, 0, stream>>>(W, W_bT, E_, H3_);
    k_cvtT<<<dim3(V_ / 64, H_ / 64), 256, 0, stream>>>(Wo, Wo_bT, H_, V_);
    k_cvt<<<(B_ * H_ / 4 + 255) / 256, 256, 0, stream>>>(h0, hbufA, B_ * H_ / 4);
    k_gather<<<M_, 128, 0, stream>>>(tok, emb, Aemb);

    // x_proj = emb(x) @ W + b0   [4000 x 3072] bf16
    k_gemm<0><<<32 * (H3_ / 128), 256, 0, stream>>>(Aemb, W_bT, bb, xproj, 32, E_, H3_);
    // GRU scan
    k_gru<<<NWG, 256, 0, stream>>>(xproj, U, bb, h0, hbufA, hbufB, hs, ctr);
    // logits = hs @ Wo + bo   [4000 x 32000] f32
    k_gemm<1><<<32 * (V_ / 128), 256, 0, stream>>>(hs, Wo_bT, bo, out, 32, H_, V_);
}